// Round 11
// baseline (158.070 us; speedup 1.0000x reference)
//
#include <hip/hip_runtime.h>

#define BB 8
#define CC 512
#define NH 8
#define HH 96
#define WW 96
#define PLANE (HH*WW)        // 9216
#define NPLANE (NH*PLANE)    // 73728
#define TROWS 14             // query rows per block (2 per wave, 7 waves)
#define TCOLS 16             // query cols per block (= MFMA M/N)
#define KROWS 20             // staged key rows: h0-3 .. h0+16
#define KCOLS 24             // staged key cols: w0-4 .. w0+19
#define NTHR 448
#define HRB 7                // ceil(96/14)
#define WCB 6

typedef float    f4    __attribute__((ext_vector_type(4), may_alias));
typedef _Float16 f16x8 __attribute__((ext_vector_type(8), may_alias));
typedef float    f32x4 __attribute__((ext_vector_type(4), may_alias));
typedef decltype(__builtin_amdgcn_cvt_pkrtz(0.f, 0.f)) h2;

union F8 { f16x8 v; h2 h[4]; f32x4 f; };

__global__ __launch_bounds__(NTHR)
void mov_kernel(const float* __restrict__ qin, const float* __restrict__ kin,
                float* __restrict__ dst, int useAtomic)
{
    const int tid = threadIdx.x;
    const int bid = blockIdx.x;
    // XCD-aware: all 42 tiles of one (b, head) slice share one XCD (bid & 7)
    const int n  = bid & 7;
    const int t2 = bid >> 3;            // 0..335
    const int b  = t2 / (HRB * WCB);
    const int tt = t2 - b * (HRB * WCB);
    const int h0 = (tt / WCB) * TROWS;
    const int w0 = (tt % WCB) * TCOLS;

    const int lane = tid & 63;
    const int wv   = tid >> 6;          // 0..6: query rows h0+2wv, h0+2wv+1
    const int g    = lane >> 4;         // k-slot 0..3
    const int mm   = lane & 15;         // M (pixel col) for A / N (key col) for B

    __shared__ f32x4 smem[KROWS * KCOLS * 8];   // 60 KB: full-d k tile

    const int kb = (b * CC + n) * PLANE;

    // ---- q loads first (latency hides under k staging) ----
    const int hq0 = min(h0 + 2 * wv,     HH - 1);
    const int hq1 = min(h0 + 2 * wv + 1, HH - 1);
    float qraw[2][16];
#pragma unroll
    for (int ks = 0; ks < 2; ++ks)
#pragma unroll
        for (int e = 0; e < 8; ++e) {
            int d = ks * 32 + g * 8 + e;
            const float* qp = qin + kb + d * NPLANE + w0 + mm;
            qraw[0][ks * 8 + e] = qp[hq0 * WW];
            qraw[1][ks * 8 + e] = qp[hq1 * WW];
        }

    // ---- stage full-d k tile: 960 tasks = 20y x 6cg x 8dg ----
    // task: load 8 d-planes x 4 cols (f4), pack d-pairs, write slot dg^(c&7)
#pragma unroll
    for (int s = 0; s < 3; ++s) {
        int t = tid + s * NTHR;
        if (t < KROWS * 6 * 8) {
            int dg = t & 7;
            int u  = t >> 3;              // 0..119
            int cg = u % 6;
            int y  = u / 6;               // 0..19
            int yg = min(max(h0 - 3 + y, 0), HH - 1);
            int xg = min(max(w0 - 4 + 4 * cg, 0), WW - 4);
            const float* kp = kin + kb + dg * 8 * NPLANE + yg * WW + xg;
            f4 v[8];
#pragma unroll
            for (int e = 0; e < 8; ++e)
                v[e] = *(const f4*)(kp + e * NPLANE);
#pragma unroll
            for (int cc = 0; cc < 4; ++cc) {
                F8 u8;
#pragma unroll
                for (int p = 0; p < 4; ++p)
                    u8.h[p] = __builtin_amdgcn_cvt_pkrtz(v[2*p][cc], v[2*p+1][cc]);
                int c = 4 * cg + cc;
                smem[(y * KCOLS + c) * 8 + (dg ^ (c & 7))] = u8.f;
            }
        }
    }

    // ---- pack A fragments (r8-verified: m=lane&15, k=g*8+e, pairs (2e,2e+1)) ----
    const float sc = 0.125f;
    f16x8 A[2][2];
#pragma unroll
    for (int rr = 0; rr < 2; ++rr)
#pragma unroll
        for (int ks = 0; ks < 2; ++ks) {
            F8 u8;
#pragma unroll
            for (int p = 0; p < 4; ++p)
                u8.h[p] = __builtin_amdgcn_cvt_pkrtz(qraw[rr][ks*8+2*p] * sc,
                                                     qraw[rr][ks*8+2*p+1] * sc);
            A[rr][ks] = u8.v;
        }

    __syncthreads();   // the only barrier

    // ---- band MFMA: B row it serves (rr=0,i=it) and (rr=1,i=it-1) ----
    f32x4 acc[2][7][2];
#pragma unroll
    for (int rr = 0; rr < 2; ++rr)
#pragma unroll
        for (int i = 0; i < 7; ++i) {
            acc[rr][i][0] = (f32x4){0.f, 0.f, 0.f, 0.f};
            acc[rr][i][1] = (f32x4){0.f, 0.f, 0.f, 0.f};
        }

    const int c0 = 1 + mm;                 // key col w0-3+mm
    const int c1 = min(17 + mm, KCOLS-1);  // key col w0+13+mm (clamped -> masked j)
#pragma unroll
    for (int ks = 0; ks < 2; ++ks)
#pragma unroll
        for (int it = 0; it < 8; ++it) {
            int yl = 2 * wv + it;          // staged row; global y = h0-3+yl
            F8 b0, b1;
            b0.f = smem[(yl * KCOLS + c0) * 8 + ((ks * 4 + g) ^ (c0 & 7))];
            b1.f = smem[(yl * KCOLS + c1) * 8 + ((ks * 4 + g) ^ (c1 & 7))];
            if (it < 7) {
                acc[0][it][0] = __builtin_amdgcn_mfma_f32_16x16x32_f16(A[0][ks], b0.v, acc[0][it][0], 0, 0, 0);
                acc[0][it][1] = __builtin_amdgcn_mfma_f32_16x16x32_f16(A[0][ks], b1.v, acc[0][it][1], 0, 0, 0);
            }
            if (it > 0) {
                acc[1][it-1][0] = __builtin_amdgcn_mfma_f32_16x16x32_f16(A[1][ks], b0.v, acc[1][it-1][0], 0, 0, 0);
                acc[1][it-1][1] = __builtin_amdgcn_mfma_f32_16x16x32_f16(A[1][ks], b1.v, acc[1][it-1][1], 0, 0, 0);
            }
        }

    // ---- register softmax epilogue (D: px = 4g+qq, key col = nt*16+mm) ----
#pragma unroll
    for (int rr = 0; rr < 2; ++rr) {
        const int hrow = h0 + 2 * wv + rr;
        if (hrow >= HH) continue;          // wave-uniform (last row-block only)
#pragma unroll
        for (int qq = 0; qq < 4; ++qq) {
            const int px = 4 * g + qq;
            const int wp = w0 + px;
            const int j0 = mm - px;
            const bool v0 = (unsigned)j0 < 7u;
            const int j  = v0 ? j0 : (16 + mm - px);
            const bool jv = ((unsigned)j < 7u) && ((unsigned)(wp + j - 3) < (unsigned)WW);
            float t[7];
#pragma unroll
            for (int i = 0; i < 7; ++i) {
                float val = v0 ? acc[rr][i][0][qq] : acc[rr][i][1][qq];
                bool iv = (unsigned)(hrow + i - 3) < (unsigned)HH;
                t[i] = (jv && iv) ? val : -1e30f;
            }
            float mx = fmaxf(fmaxf(fmaxf(t[0], t[1]), fmaxf(t[2], t[3])),
                             fmaxf(fmaxf(t[4], t[5]), t[6]));
#pragma unroll
            for (int s = 1; s <= 8; s <<= 1)
                mx = fmaxf(mx, __shfl_xor(mx, s));
            float l = 0.f, di = 0.f;
#pragma unroll
            for (int i = 0; i < 7; ++i) {
                float e = __expf(t[i] - mx);
                l += e; di += e * (float)(i - 3);
            }
            float dj = (float)(j - 3) * l;          // j fixed per lane
#pragma unroll
            for (int s = 1; s <= 8; s <<= 1) {
                l  += __shfl_xor(l, s);
                di += __shfl_xor(di, s);
                dj += __shfl_xor(dj, s);
            }
            if (mm == 0) {                           // one writer lane per (g,qq)
                float inv = 1.0f / (l * 8.0f);       // /8 = head mean
                if (useAtomic) {
                    atomicAdd(dst + (b * 2 + 0) * PLANE + hrow * WW + wp, di * inv);
                    atomicAdd(dst + (b * 2 + 1) * PLANE + hrow * WW + wp, dj * inv);
                } else {
                    dst[((b * NH + n) * 2 + 0) * PLANE + hrow * WW + wp] = di * inv;
                    dst[((b * NH + n) * 2 + 1) * PLANE + hrow * WW + wp] = dj * inv;
                }
            }
        }
    }
}

__global__ __launch_bounds__(256)
void reduce_kernel(const float* __restrict__ ws, float* __restrict__ out)
{
    int t = blockIdx.x * 256 + threadIdx.x;
    if (t >= BB * 2 * PLANE) return;
    int b = t / (2 * PLANE);
    int r = t - b * 2 * PLANE;          // comp*PLANE + hw
    float s = 0.f;
#pragma unroll
    for (int n = 0; n < NH; ++n)
        s += ws[(b * NH + n) * 2 * PLANE + r];
    out[t] = s;
}

extern "C" void kernel_launch(void* const* d_in, const int* in_sizes, int n_in,
                              void* d_out, int out_size, void* d_ws, size_t ws_size,
                              hipStream_t stream) {
    const float* q = (const float*)d_in[0];
    const float* k = (const float*)d_in[1];
    float* out = (float*)d_out;

    const size_t need = (size_t)BB * NH * 2 * PLANE * sizeof(float);   // 4.72 MB
    const int useAtomic = (ws_size < need) ? 1 : 0;

    dim3 grid(BB * NH * HRB * WCB);     // 2688
    dim3 block(NTHR);

    if (useAtomic) {
        hipMemsetAsync(out, 0, (size_t)out_size * sizeof(float), stream);
        hipLaunchKernelGGL(mov_kernel, grid, block, 0, stream, q, k, out, 1);
    } else {
        float* ws = (float*)d_ws;
        hipLaunchKernelGGL(mov_kernel, grid, block, 0, stream, q, k, ws, 0);
        dim3 g2((BB * 2 * PLANE + 255) / 256);   // 576
        hipLaunchKernelGGL(reduce_kernel, g2, dim3(256), 0, stream, ws, out);
    }
}

// Round 12
// 102.557 us; speedup vs baseline: 1.5413x; 1.5413x over previous
//
#include <hip/hip_runtime.h>

#define BB 8
#define CC 512
#define NH 8
#define HH 96
#define WW 96
#define PLANE (HH*WW)        // 9216
#define NPLANE (NH*PLANE)    // 73728
#define TROWS 4              // query rows per block (1 per wave)
#define TCOLS 16
#define KROWS 10             // staged key rows: h0-3 .. h0+6
#define KCOLS 32             // staged key cols: w0-4 .. w0+27
#define NTHR 256
#define QPAD 40              // q row pad (h2 units): 4-way max on A-reads

typedef float    f4    __attribute__((ext_vector_type(4), may_alias));
typedef float    f2    __attribute__((ext_vector_type(2), may_alias));
typedef _Float16 f16x8 __attribute__((ext_vector_type(8), may_alias));
typedef float    f32x4 __attribute__((ext_vector_type(4), may_alias));
typedef decltype(__builtin_amdgcn_cvt_pkrtz(0.f, 0.f)) h2;

union F8 { f16x8 v; h2 h[4]; f32x4 f; };
union F4 { f2 f; h2 h[2]; };

__global__ __launch_bounds__(NTHR)
void mov_kernel(const float* __restrict__ qin, const float* __restrict__ kin,
                float* __restrict__ dst, int useAtomic)
{
    const int tid = threadIdx.x;
    const int bid = blockIdx.x;
    // XCD-aware: all 144 tiles of one (b, head) slice share one XCD (bid & 7)
    const int n  = bid & 7;
    const int t2 = bid >> 3;            // 0..1151
    const int b  = t2 / 144;
    const int tt = t2 - b * 144;
    const int h0 = (tt / 6) * TROWS;
    const int w0 = (tt % 6) * TCOLS;

    const int lane = tid & 63;
    const int wv   = tid >> 6;          // wave 0..3 -> query row h0+wv
    const int g    = lane >> 4;         // k-slot 0..3
    const int mm   = lane & 15;         // M (pixel col) for A / N (key col) for B
    const int hrow = h0 + wv;

    __shared__ f32x4 ksm[KROWS * KCOLS * 8];       // 40960 B
    __shared__ h2    qsm[TROWS * TCOLS * QPAD];    // 10240 B  -> 50 KB total

    const int kb = (b * CC + n) * PLANE;
    const float sc = 0.125f;

    // ---- issue ALL global loads up front (coalesced f4, cu-fastest order) ----
    // k: 1280 tasks: cu = t&7 (4 cols), dp = (t>>3)&15 (4 planes), y = t>>7
    f4 kv[5][4];
#pragma unroll
    for (int s = 0; s < 5; ++s) {
        int t  = tid + s * NTHR;
        int cu = t & 7, dp = (t >> 3) & 15, y = t >> 7;
        int yg = min(max(h0 - 3 + y, 0), HH - 1);
        int xg = min(max(w0 - 4 + 4 * cu, 0), WW - 4);
        const float* kp = kin + kb + 4 * dp * NPLANE + yg * WW + xg;
#pragma unroll
        for (int e = 0; e < 4; ++e)
            kv[s][e] = *(const f4*)(kp + e * NPLANE);
    }
    // q: 512 tasks: cq = t&3 (4 cols), p = (t>>2)&31 (d-pair), r = t>>7
    f4 qv[2][2];
#pragma unroll
    for (int s = 0; s < 2; ++s) {
        int t  = tid + s * NTHR;
        int cq = t & 3, p = (t >> 2) & 31, r = t >> 7;
        const float* qp = qin + kb + 2 * p * NPLANE + (h0 + r) * WW + w0 + 4 * cq;
        qv[s][0] = *(const f4*)(qp);
        qv[s][1] = *(const f4*)(qp + NPLANE);
    }

    // ---- pack & write k: slot sl = dp>>1 XOR (c&7), half = dp&1 (b64) ----
#pragma unroll
    for (int s = 0; s < 5; ++s) {
        int t  = tid + s * NTHR;
        int cu = t & 7, dp = (t >> 3) & 15, y = t >> 7;
        int sl = dp >> 1, hf = dp & 1;
#pragma unroll
        for (int cc = 0; cc < 4; ++cc) {
            int c = 4 * cu + cc;
            F4 u;
            u.h[0] = __builtin_amdgcn_cvt_pkrtz(kv[s][0][cc], kv[s][1][cc]);
            u.h[1] = __builtin_amdgcn_cvt_pkrtz(kv[s][2][cc], kv[s][3][cc]);
            ((f2*)&ksm[(y * KCOLS + c) * 8 + (sl ^ (c & 7))])[hf] = u.f;
        }
    }
    // ---- pack & write q (scale folded in) ----
#pragma unroll
    for (int s = 0; s < 2; ++s) {
        int t  = tid + s * NTHR;
        int cq = t & 3, p = (t >> 2) & 31, r = t >> 7;
#pragma unroll
        for (int cc = 0; cc < 4; ++cc)
            qsm[(r * TCOLS + 4 * cq + cc) * QPAD + p] =
                __builtin_amdgcn_cvt_pkrtz(qv[s][0][cc] * sc, qv[s][1][cc] * sc);
    }

    __syncthreads();   // the only barrier

    // ---- A fragments from LDS (r8-verified: m=lane&15, k=g*8+e) ----
    f16x8 A[2];
#pragma unroll
    for (int ks = 0; ks < 2; ++ks) {
        F8 u;
        u.f = *(const f32x4*)&qsm[(wv * TCOLS + mm) * QPAD + ks * 16 + g * 4];
        A[ks] = u.v;
    }

    // ---- band MFMA ----
    f32x4 acc[7][2];
#pragma unroll
    for (int i = 0; i < 7; ++i) {
        acc[i][0] = (f32x4){0.f, 0.f, 0.f, 0.f};
        acc[i][1] = (f32x4){0.f, 0.f, 0.f, 0.f};
    }
#pragma unroll
    for (int ks = 0; ks < 2; ++ks)
#pragma unroll
        for (int i = 0; i < 7; ++i) {
            int yl = wv + i;                       // global y = hrow-3+i
            int sx = (ks * 4 + g) ^ (mm & 7);      // (16+mm)&7 == mm&7
            F8 b0, b1;
            b0.f = ksm[(yl * KCOLS + mm) * 8 + sx];
            b1.f = ksm[(yl * KCOLS + 16 + mm) * 8 + sx];
            acc[i][0] = __builtin_amdgcn_mfma_f32_16x16x32_f16(A[ks], b0.v, acc[i][0], 0, 0, 0);
            acc[i][1] = __builtin_amdgcn_mfma_f32_16x16x32_f16(A[ks], b1.v, acc[i][1], 0, 0, 0);
        }

    // ---- register-only softmax epilogue (r9-verified D layout) ----
#pragma unroll
    for (int qq = 0; qq < 4; ++qq) {
        const int px = 4 * g + qq;
        const int wp = w0 + px;
        const int j0 = mm - px - 1;
        const bool v0 = (unsigned)j0 < 7u;
        const int j  = v0 ? j0 : j0 + 16;
        const bool jv = ((unsigned)j < 7u) && ((unsigned)(wp + j - 3) < (unsigned)WW);
        float t[7];
#pragma unroll
        for (int i = 0; i < 7; ++i) {
            float val = v0 ? acc[i][0][qq] : acc[i][1][qq];
            bool iv = (unsigned)(hrow + i - 3) < (unsigned)HH;
            t[i] = (jv && iv) ? val : -1e30f;
        }
        float mx = fmaxf(fmaxf(fmaxf(t[0], t[1]), fmaxf(t[2], t[3])),
                         fmaxf(fmaxf(t[4], t[5]), t[6]));
#pragma unroll
        for (int s = 1; s <= 8; s <<= 1)
            mx = fmaxf(mx, __shfl_xor(mx, s));
        float l = 0.f, di = 0.f;
#pragma unroll
        for (int i = 0; i < 7; ++i) {
            float e = __expf(t[i] - mx);
            l += e; di += e * (float)(i - 3);
        }
        float dj = (float)(j - 3) * l;             // j fixed per lane
#pragma unroll
        for (int s = 1; s <= 8; s <<= 1) {
            l  += __shfl_xor(l, s);
            di += __shfl_xor(di, s);
            dj += __shfl_xor(dj, s);
        }
        if (mm == px) {                            // one writer lane per pixel
            float inv = 1.0f / (l * 8.0f);         // /8 = head mean
            if (useAtomic) {
                atomicAdd(dst + (b * 2 + 0) * PLANE + hrow * WW + wp, di * inv);
                atomicAdd(dst + (b * 2 + 1) * PLANE + hrow * WW + wp, dj * inv);
            } else {
                dst[((b * NH + n) * 2 + 0) * PLANE + hrow * WW + wp] = di * inv;
                dst[((b * NH + n) * 2 + 1) * PLANE + hrow * WW + wp] = dj * inv;
            }
        }
    }
}

__global__ __launch_bounds__(256)
void reduce_kernel(const float* __restrict__ ws, float* __restrict__ out)
{
    int t = blockIdx.x * 256 + threadIdx.x;
    if (t >= BB * 2 * PLANE) return;
    int b = t / (2 * PLANE);
    int r = t - b * 2 * PLANE;
    float s = 0.f;
#pragma unroll
    for (int n = 0; n < NH; ++n)
        s += ws[(b * NH + n) * 2 * PLANE + r];
    out[t] = s;
}

extern "C" void kernel_launch(void* const* d_in, const int* in_sizes, int n_in,
                              void* d_out, int out_size, void* d_ws, size_t ws_size,
                              hipStream_t stream) {
    const float* q = (const float*)d_in[0];
    const float* k = (const float*)d_in[1];
    float* out = (float*)d_out;

    const size_t need = (size_t)BB * NH * 2 * PLANE * sizeof(float);   // 4.72 MB
    const int useAtomic = (ws_size < need) ? 1 : 0;

    dim3 grid(BB * NH * (HH / TROWS) * (WW / TCOLS));   // 9216
    dim3 block(NTHR);

    if (useAtomic) {
        hipMemsetAsync(out, 0, (size_t)out_size * sizeof(float), stream);
        hipLaunchKernelGGL(mov_kernel, grid, block, 0, stream, q, k, out, 1);
    } else {
        float* ws = (float*)d_ws;
        hipLaunchKernelGGL(mov_kernel, grid, block, 0, stream, q, k, ws, 0);
        dim3 g2((BB * 2 * PLANE + 255) / 256);   // 576
        hipLaunchKernelGGL(reduce_kernel, g2, dim3(256), 0, stream, ws, out);
    }
}